// Round 6
// baseline (2121.179 us; speedup 1.0000x reference)
//
#include <hip/hip_runtime.h>
#include <hip/hip_bf16.h>

// MPNN GNN: V=12500 (feat 32), E=200000 (feat 16), H=32, 6 steps.
// msg[e,o] = sum_k a[e,k]*T[src[e],k,o] + Tb[src[e],o],  a loop-invariant.
// R5 lessons: (1) b128 from a 4KB/node tile is inherently 4-way bank-conflicted
// (1.76e7 conflicts) -> use [n][k][o] + b32, bank = lane o, conflict-free.
// (2) f32 atomics write through to the coherence point: 25.6M atomics = 100 MB
// fabric writes -> full k=128 in LDS (NB=4, 64KB, 2 blk/CU) = ONE atomic per
// (e,o): 6.4M/step, ~27 MB.

#define NB 4  // src nodes per k_step block

// ---------------- node projection: h = relu(nf@w1+b1)@w2+b2 ----------------
__global__ __launch_bounds__(256) void k_proj(
    const float* __restrict__ nf, const float* __restrict__ w1,
    const float* __restrict__ b1, const float* __restrict__ w2,
    const float* __restrict__ b2, float* __restrict__ hseq, int nV) {
  __shared__ float sw1[1024], sw2[1024], sb1[32], sb2[32];
  __shared__ float sx[8][32], st1[8][32];
  int t = threadIdx.x;
  int v0 = blockIdx.x * 8;
  for (int i = t; i < 1024; i += 256) { sw1[i] = w1[i]; sw2[i] = w2[i]; }
  if (t < 32) { sb1[t] = b1[t]; sb2[t] = b2[t]; }
  {
    int g = v0 * 32 + t;
    sx[t >> 5][t & 31] = (g < nV * 32) ? nf[g] : 0.f;
  }
  __syncthreads();
  int n = t >> 5, j = t & 31;
  float s = sb1[j];
#pragma unroll
  for (int i = 0; i < 32; i++) s += sx[n][i] * sw1[i * 32 + j];
  st1[n][j] = fmaxf(s, 0.f);
  __syncthreads();
  float h = sb2[j];
#pragma unroll
  for (int i = 0; i < 32; i++) h += st1[n][i] * sw2[i * 32 + j];
  if (v0 + n < nV) hseq[(size_t)(v0 + n) * 32 + j] = h;
}

// ---------------- edge hidden: a = relu(ef@e_w1+e_b1), (E x 128) f32 -------
__global__ __launch_bounds__(256) void k_edgeh(
    const float* __restrict__ ef, const float* __restrict__ w1,
    const float* __restrict__ b1, float* __restrict__ a, int nE) {
  __shared__ float sw1[16 * 128], sb1[128], sef[2 * 16];
  int t = threadIdx.x;
  for (int i = t; i < 2048; i += 256) sw1[i] = w1[i];
  if (t < 128) sb1[t] = b1[t];
  int e0 = blockIdx.x * 2;
  if (t < 32) {
    int e = e0 + (t >> 4);
    if (e < nE) sef[t] = ef[(size_t)e * 16 + (t & 15)];
  }
  __syncthreads();
  int el = t >> 7, c = t & 127;
  int e = e0 + el;
  if (e >= nE) return;
  float s = sb1[c];
#pragma unroll
  for (int i = 0; i < 16; i++) s += sef[el * 16 + i] * sw1[i * 128 + c];
  a[(size_t)e * 128 + c] = fmaxf(s, 0.f);
}

// ---------------- CSR by src ----------------
__global__ __launch_bounds__(256) void k_count(const int* __restrict__ key,
                                               int* __restrict__ counts, int nE) {
  int e = blockIdx.x * 256 + threadIdx.x;
  if (e < nE) atomicAdd(&counts[key[e]], 1);
}

__global__ __launch_bounds__(1024) void k_scan(const int* __restrict__ counts,
                                               int* __restrict__ row_ptr, int nV) {
  __shared__ int buf[1024];
  __shared__ int s_off;
  int t = threadIdx.x;
  if (t == 0) s_off = 0;
  __syncthreads();
  for (int base = 0; base < nV; base += 1024) {
    int x = (base + t < nV) ? counts[base + t] : 0;
    buf[t] = x;
    __syncthreads();
    for (int d = 1; d < 1024; d <<= 1) {
      int v2 = (t >= d) ? buf[t - d] : 0;
      __syncthreads();
      buf[t] += v2;
      __syncthreads();
    }
    int incl = buf[t];
    int off = s_off;
    __syncthreads();
    if (base + t < nV) row_ptr[base + t] = off + incl - x;  // exclusive
    if (t == 1023) s_off = off + incl;
    __syncthreads();
  }
  if (t == 0) row_ptr[nV] = s_off;
}

__global__ __launch_bounds__(256) void k_copy(const int* __restrict__ row_ptr,
                                              int* __restrict__ cursor, int nV) {
  int v = blockIdx.x * 256 + threadIdx.x;
  if (v < nV) cursor[v] = row_ptr[v];
}

__global__ __launch_bounds__(256) void k_scatter(const int* __restrict__ key,
                                                 int* __restrict__ cursor,
                                                 int* __restrict__ perm, int nE) {
  int e = blockIdx.x * 256 + threadIdx.x;
  if (e < nE) {
    int p = atomicAdd(&cursor[key[e]], 1);
    perm[p] = e;
  }
}

// ---------------- per-step: full-k T-in-LDS + message + single atomic ------
// Block = NB src nodes, full k=128. LDS T = NB*4096 f32 = 64 KB, 2 blk/CU.
// T layout [n][k][o]: edge loop reads sT[n*4096 + k*32 + o] -> bank = o,
// conflict-free b32. One atomicAdd per (edge, o).
__global__ __launch_bounds__(256) void k_step(
    const float* __restrict__ hseq, const float* __restrict__ w2,
    const float* __restrict__ b2, const float* __restrict__ a,
    const int* __restrict__ row_ptr, const int* __restrict__ perm,
    const int* __restrict__ dst, float* __restrict__ agg, int nV) {
  __shared__ float sT[NB * 4096];
  __shared__ float sh[NB][32];
  __shared__ float sTb[NB][32];
  __shared__ int s_rp[NB + 1];
  int t = threadIdx.x;
  int v0 = blockIdx.x * NB;
  if (t <= NB) {
    int v = v0 + t;
    if (v > nV) v = nV;
    s_rp[t] = row_ptr[v];
  }
  if (t < NB * 32) {
    int n = t >> 5, v = v0 + n;
    sh[n][t & 31] = (v < nV) ? hseq[(size_t)v * 32 + (t & 31)] : 0.f;
  }
  __syncthreads();
  if (s_rp[0] == s_rp[NB]) return;  // group has no out-edges (block-uniform)

  // T tile: all 128 k, NB nodes. 256 threads x 16 iters over (k,o).
  for (int idx = t; idx < 4096; idx += 256) {
    int k = idx >> 5, o = idx & 31;
    const float* w = w2 + (size_t)k * 1024 + o;  // + i*32
    float acc[NB];
#pragma unroll
    for (int n = 0; n < NB; n++) acc[n] = 0.f;
#pragma unroll 8
    for (int i = 0; i < 32; i++) {
      float wv = w[i * 32];
#pragma unroll
      for (int n = 0; n < NB; n++) acc[n] += sh[n][i] * wv;
    }
#pragma unroll
    for (int n = 0; n < NB; n++) sT[(n << 12) + idx] = acc[n];
  }
  // Tb (edge-MLP bias term)
  if (t < NB * 32) {
    int n = t >> 5, o = t & 31;
    float s = 0.f;
#pragma unroll
    for (int i = 0; i < 32; i++) s += sh[n][i] * b2[i * 32 + o];
    sTb[n][o] = s;
  }
  __syncthreads();

  int o = t & 31, sub = t >> 5;  // 8 edge slots x 32 output lanes
  int beg = s_rp[0], end = s_rp[NB];
  int n = 0;
  for (int idx = beg + sub; idx < end; idx += 8) {
    while (idx >= s_rp[n + 1]) n++;  // monotonic across iterations
    int e = perm[idx];
    const float4* a4 = (const float4*)(a + (size_t)e * 128);
    const float* Tn = sT + (n << 12) + o;
    float s = sTb[n][o];
#pragma unroll 4
    for (int kq = 0; kq < 32; kq++) {
      float4 av = a4[kq];
      s += av.x * Tn[(kq * 4 + 0) << 5];
      s += av.y * Tn[(kq * 4 + 1) << 5];
      s += av.z * Tn[(kq * 4 + 2) << 5];
      s += av.w * Tn[(kq * 4 + 3) << 5];
    }
    atomicAdd(&agg[(size_t)dst[e] * 32 + o], s);
  }
}

// ---------------- fused agg-read + GRU: block = 8 nodes x 32 o -------------
__global__ __launch_bounds__(256) void k_agru(
    const float* __restrict__ agg, const float* __restrict__ cbias,
    const float* __restrict__ wih, const float* __restrict__ whh,
    const float* __restrict__ bih, const float* __restrict__ bhh,
    float* __restrict__ hseq, int nV) {
  __shared__ float swT[2][32 * 97];  // transposed, stride-97 pad
  __shared__ float sb[2][96], scb[32];
  __shared__ float sx[8][32], shd[8][32];
  int t = threadIdx.x;
  int v0 = blockIdx.x * 8;
  for (int idx = t; idx < 3072; idx += 256) {
    int row = idx >> 5, i = idx & 31;
    swT[0][i * 97 + row] = wih[idx];
    swT[1][i * 97 + row] = whh[idx];
  }
  if (t < 96) { sb[0][t] = bih[t]; sb[1][t] = bhh[t]; }
  if (t < 32) scb[t] = cbias[t];
  {
    int n = t >> 5, v = v0 + n, j = t & 31;
    shd[n][j] = (v < nV) ? hseq[(size_t)v * 32 + j] : 0.f;
    sx[n][j] = (v < nV) ? fmaxf(agg[(size_t)v * 32 + j] + cbias[j], 0.f) : 0.f;
  }
  __syncthreads();
  int n = t >> 5, o = t & 31;
  int v = v0 + n;
  if (v >= nV) return;
  float gir = sb[0][o], giz = sb[0][32 + o], gin = sb[0][64 + o];
  float ghr = sb[1][o], ghz = sb[1][32 + o], ghn = sb[1][64 + o];
#pragma unroll
  for (int i = 0; i < 32; i++) {
    float xi = sx[n][i], hi = shd[n][i];
    gir += xi * swT[0][i * 97 + o];
    giz += xi * swT[0][i * 97 + 32 + o];
    gin += xi * swT[0][i * 97 + 64 + o];
    ghr += hi * swT[1][i * 97 + o];
    ghz += hi * swT[1][i * 97 + 32 + o];
    ghn += hi * swT[1][i * 97 + 64 + o];
  }
  float r = 1.f / (1.f + __expf(-(gir + ghr)));
  float z = 1.f / (1.f + __expf(-(giz + ghz)));
  float ng = tanhf(gin + r * ghn);
  hseq[(size_t)v * 32 + o] = (1.f - z) * ng + z * shd[n][o];
}

// ---------------- decoder: out = relu(h@dw1+db1)@dw2+db2  (V x 64) ---------
__global__ __launch_bounds__(256) void k_dec(
    const float* __restrict__ hseq, const float* __restrict__ w1,
    const float* __restrict__ b1, const float* __restrict__ w2,
    const float* __restrict__ b2, float* __restrict__ out, int nV) {
  __shared__ float sw1[1024], sb1[32], sw2[2048], sb2[64];
  __shared__ float sx[4][32], st1[4][32];
  int t = threadIdx.x;
  int v0 = blockIdx.x * 4;
  for (int i = t; i < 1024; i += 256) sw1[i] = w1[i];
  for (int i = t; i < 2048; i += 256) sw2[i] = w2[i];
  if (t < 32) sb1[t] = b1[t];
  if (t < 64) sb2[t] = b2[t];
  if (t < 128) {
    int g = v0 * 32 + t;
    sx[t >> 5][t & 31] = (g < nV * 32) ? hseq[g] : 0.f;
  }
  __syncthreads();
  if (t < 128) {
    int n = t >> 5, j = t & 31;
    float s = sb1[j];
#pragma unroll
    for (int i = 0; i < 32; i++) s += sx[n][i] * sw1[i * 32 + j];
    st1[n][j] = fmaxf(s, 0.f);
  }
  __syncthreads();
  int n = t >> 6, j = t & 63;
  float s = sb2[j];
#pragma unroll
  for (int i = 0; i < 32; i++) s += st1[n][i] * sw2[i * 64 + j];
  if (v0 + n < nV) out[(size_t)(v0 + n) * 64 + j] = s;
}

extern "C" void kernel_launch(void* const* d_in, const int* in_sizes, int n_in,
                              void* d_out, int out_size, void* d_ws, size_t ws_size,
                              hipStream_t stream) {
  const float* node_feats = (const float*)d_in[0];
  const float* edge_feats = (const float*)d_in[1];
  const int* src = (const int*)d_in[2];
  const int* dst = (const int*)d_in[3];
  const float* proj_w1 = (const float*)d_in[4];
  const float* proj_b1 = (const float*)d_in[5];
  const float* proj_w2 = (const float*)d_in[6];
  const float* proj_b2 = (const float*)d_in[7];
  const float* e_w1 = (const float*)d_in[8];
  const float* e_b1 = (const float*)d_in[9];
  const float* e_w2 = (const float*)d_in[10];
  const float* e_b2 = (const float*)d_in[11];
  const float* conv_bias = (const float*)d_in[12];
  const float* gru_wih = (const float*)d_in[13];
  const float* gru_whh = (const float*)d_in[14];
  const float* gru_bih = (const float*)d_in[15];
  const float* gru_bhh = (const float*)d_in[16];
  const float* dec_w1 = (const float*)d_in[17];
  const float* dec_b1 = (const float*)d_in[18];
  const float* dec_w2 = (const float*)d_in[19];
  const float* dec_b2 = (const float*)d_in[20];
  float* out = (float*)d_out;

  const int nV = in_sizes[0] / 32;
  const int nE = in_sizes[2];

  // workspace carve-up (~107 MB; known-safe)
  char* base = (char*)d_ws;
  size_t off = 0;
  auto carve = [&](size_t bytes) {
    void* r = base + off;
    off = (off + bytes + 255) & ~(size_t)255;
    return r;
  };
  float* a = (float*)carve((size_t)nE * 128 * 4);
  float* hseq = (float*)carve((size_t)nV * 32 * 4);
  float* agg = (float*)carve((size_t)nV * 32 * 4);
  int* countsS = (int*)carve((size_t)nV * 4);
  int* rpS = (int*)carve((size_t)(nV + 1) * 4);
  int* curS = (int*)carve((size_t)nV * 4);
  int* permS = (int*)carve((size_t)nE * 4);
  (void)ws_size;

  const int TB = 256;
  int gE = (nE + TB - 1) / TB;
  int g8 = (nV + 7) / 8;
  int g4 = (nV + 3) / 4;
  int gStep = (nV + NB - 1) / NB;

  // setup
  k_proj<<<g8, TB, 0, stream>>>(node_feats, proj_w1, proj_b1, proj_w2, proj_b2, hseq, nV);
  k_edgeh<<<(nE + 1) / 2, TB, 0, stream>>>(edge_feats, e_w1, e_b1, a, nE);
  hipMemsetAsync(countsS, 0, (size_t)nV * 4, stream);
  k_count<<<gE, TB, 0, stream>>>(src, countsS, nE);
  k_scan<<<1, 1024, 0, stream>>>(countsS, rpS, nV);
  k_copy<<<(nV + TB - 1) / TB, TB, 0, stream>>>(rpS, curS, nV);
  k_scatter<<<gE, TB, 0, stream>>>(src, curS, permS, nE);

  // 6 message-passing steps
  for (int step = 0; step < 6; step++) {
    hipMemsetAsync(agg, 0, (size_t)nV * 32 * 4, stream);
    k_step<<<gStep, TB, 0, stream>>>(hseq, e_w2, e_b2, a, rpS, permS, dst, agg, nV);
    k_agru<<<g8, TB, 0, stream>>>(agg, conv_bias, gru_wih, gru_whh,
                                  gru_bih, gru_bhh, hseq, nV);
  }

  // decoder
  k_dec<<<g4, TB, 0, stream>>>(hseq, dec_w1, dec_b1, dec_w2, dec_b2, out, nV);
}

// Round 7
// 1462.578 us; speedup vs baseline: 1.4503x; 1.4503x over previous
//
#include <hip/hip_runtime.h>
#include <hip/hip_bf16.h>

// MPNN GNN: V=12500 (feat 32), E=200000 (feat 16), H=32, 6 steps.
// msg[e,o] = sum_k a[e,k]*T[src[e],k,o] + Tb[src[e],o],  a loop-invariant.
// R6 lesson: scattered a[perm[idx]] reads at 8 waves/CU = latency-bound
// (260 GB/s, 330us/step). R7: edge MLP written PRE-PERMUTED quarter-major
// (aq[kc][idx][32]) -> sequential streaming + L3 residency; k-quartered T
// (16 KB) + CAP=128 LDS msg tile accumulates quarters locally -> still one
// atomic per (e,o); ~34 KB LDS -> 4 blk/CU, 16 waves.

#define NB 4    // src nodes per k_step block
#define CAP 128 // edge chunk per LDS msg tile

// ---------------- node projection: h = relu(nf@w1+b1)@w2+b2 ----------------
__global__ __launch_bounds__(256) void k_proj(
    const float* __restrict__ nf, const float* __restrict__ w1,
    const float* __restrict__ b1, const float* __restrict__ w2,
    const float* __restrict__ b2, float* __restrict__ hseq, int nV) {
  __shared__ float sw1[1024], sw2[1024], sb1[32], sb2[32];
  __shared__ float sx[8][32], st1[8][32];
  int t = threadIdx.x;
  int v0 = blockIdx.x * 8;
  for (int i = t; i < 1024; i += 256) { sw1[i] = w1[i]; sw2[i] = w2[i]; }
  if (t < 32) { sb1[t] = b1[t]; sb2[t] = b2[t]; }
  {
    int g = v0 * 32 + t;
    sx[t >> 5][t & 31] = (g < nV * 32) ? nf[g] : 0.f;
  }
  __syncthreads();
  int n = t >> 5, j = t & 31;
  float s = sb1[j];
#pragma unroll
  for (int i = 0; i < 32; i++) s += sx[n][i] * sw1[i * 32 + j];
  st1[n][j] = fmaxf(s, 0.f);
  __syncthreads();
  float h = sb2[j];
#pragma unroll
  for (int i = 0; i < 32; i++) h += st1[n][i] * sw2[i * 32 + j];
  if (v0 + n < nV) hseq[(size_t)(v0 + n) * 32 + j] = h;
}

// -------- edge hidden, fused permute+quarter-transpose:
// aq[kc][idx][o32] = relu(ef[perm[idx]]@e_w1+e_b1)[kc*32+o32]
__global__ __launch_bounds__(256) void k_edgeha(
    const float* __restrict__ ef, const float* __restrict__ w1,
    const float* __restrict__ b1, const int* __restrict__ perm,
    float* __restrict__ aq, int nE) {
  __shared__ float sw1[16 * 128], sb1[128], sef[2 * 16];
  int t = threadIdx.x;
  for (int i = t; i < 2048; i += 256) sw1[i] = w1[i];
  if (t < 128) sb1[t] = b1[t];
  int i0 = blockIdx.x * 2;
  if (t < 32) {
    int ii = i0 + (t >> 4);
    if (ii < nE) {
      int e = perm[ii];
      sef[t] = ef[(size_t)e * 16 + (t & 15)];
    }
  }
  __syncthreads();
  int el = t >> 7, c = t & 127;
  int ii = i0 + el;
  if (ii >= nE) return;
  float s = sb1[c];
#pragma unroll
  for (int i = 0; i < 16; i++) s += sef[el * 16 + i] * sw1[i * 128 + c];
  s = fmaxf(s, 0.f);
  aq[(size_t)(c >> 5) * nE * 32 + (size_t)ii * 32 + (c & 31)] = s;
}

// ---------------- CSR by src ----------------
__global__ __launch_bounds__(256) void k_count(const int* __restrict__ key,
                                               int* __restrict__ counts, int nE) {
  int e = blockIdx.x * 256 + threadIdx.x;
  if (e < nE) atomicAdd(&counts[key[e]], 1);
}

__global__ __launch_bounds__(1024) void k_scan(const int* __restrict__ counts,
                                               int* __restrict__ row_ptr, int nV) {
  __shared__ int buf[1024];
  __shared__ int s_off;
  int t = threadIdx.x;
  if (t == 0) s_off = 0;
  __syncthreads();
  for (int base = 0; base < nV; base += 1024) {
    int x = (base + t < nV) ? counts[base + t] : 0;
    buf[t] = x;
    __syncthreads();
    for (int d = 1; d < 1024; d <<= 1) {
      int v2 = (t >= d) ? buf[t - d] : 0;
      __syncthreads();
      buf[t] += v2;
      __syncthreads();
    }
    int incl = buf[t];
    int off = s_off;
    __syncthreads();
    if (base + t < nV) row_ptr[base + t] = off + incl - x;  // exclusive
    if (t == 1023) s_off = off + incl;
    __syncthreads();
  }
  if (t == 0) row_ptr[nV] = s_off;
}

__global__ __launch_bounds__(256) void k_copy(const int* __restrict__ row_ptr,
                                              int* __restrict__ cursor, int nV) {
  int v = blockIdx.x * 256 + threadIdx.x;
  if (v < nV) cursor[v] = row_ptr[v];
}

// scatter edge ids by src; also capture dstp[idx] = dst of the permuted edge
__global__ __launch_bounds__(256) void k_scatter(const int* __restrict__ key,
                                                 const int* __restrict__ dst,
                                                 int* __restrict__ cursor,
                                                 int* __restrict__ perm,
                                                 int* __restrict__ dstp, int nE) {
  int e = blockIdx.x * 256 + threadIdx.x;
  if (e < nE) {
    int p = atomicAdd(&cursor[key[e]], 1);
    perm[p] = e;
    dstp[p] = dst[e];
  }
}

// ---------------- per-step: quartered T + LDS msg tile + single atomic -----
// Block = NB src nodes. For each CAP-chunk of the group's edges:
//   msg[le][o] = Tb; for kc in 0..3: {T-quarter in LDS; msg += aq-quarter x T}
//   flush: one atomicAdd per (edge,o).
// T layout [n][kl][o]: bank = o, conflict-free.
__global__ __launch_bounds__(256) void k_step(
    const float* __restrict__ hseq, const float* __restrict__ w2,
    const float* __restrict__ b2, const float* __restrict__ aq,
    const int* __restrict__ row_ptr, const int* __restrict__ dstp,
    float* __restrict__ agg, int nV, int nE) {
  __shared__ float sT[NB * 1024];    // [n][kl][o], quarter
  __shared__ float smsg[CAP * 32];   // [le][o]
  __shared__ float sh[NB][32];
  __shared__ float sTb[NB][32];
  __shared__ int s_rp[NB + 1];
  int t = threadIdx.x;
  int v0 = blockIdx.x * NB;
  if (t <= NB) {
    int v = v0 + t;
    if (v > nV) v = nV;
    s_rp[t] = row_ptr[v];
  }
  if (t < NB * 32) {
    int n = t >> 5, v = v0 + n;
    sh[n][t & 31] = (v < nV) ? hseq[(size_t)v * 32 + (t & 31)] : 0.f;
  }
  __syncthreads();
  int beg = s_rp[0], end = s_rp[NB];
  if (beg == end) return;  // block-uniform exit

  // Tb[n][o] = sum_i h[n][i] * e_b2[i*32+o]
  if (t < NB * 32) {
    int n = t >> 5, o = t & 31;
    float s = 0.f;
#pragma unroll
    for (int i = 0; i < 32; i++) s += sh[n][i] * b2[i * 32 + o];
    sTb[n][o] = s;
  }
  __syncthreads();

  int o = t & 31, sub = t >> 5;  // 8 edge slots x 32 output lanes

  for (int cbase = beg; cbase < end; cbase += CAP) {
    int cend = cbase + CAP < end ? cbase + CAP : end;
    // init msg tile with Tb (slot-strided walk)
    {
      int n = 0;
      for (int idx = cbase + sub; idx < cend; idx += 8) {
        while (idx >= s_rp[n + 1]) n++;
        smsg[(idx - cbase) * 32 + o] = sTb[n][o];
      }
    }
    for (int kc = 0; kc < 4; kc++) {
      __syncthreads();  // prev edge pass (or msg init) complete before sT overwrite
      // T-quarter: kl in [0,32) -> k = kc*32+kl
      for (int pos = t; pos < 1024; pos += 256) {
        int kl = pos >> 5, oo = pos & 31;
        const float* w = w2 + (size_t)(kc * 32 + kl) * 1024 + oo;  // + i*32
        float acc[NB];
#pragma unroll
        for (int n = 0; n < NB; n++) acc[n] = 0.f;
#pragma unroll 8
        for (int i = 0; i < 32; i++) {
          float wv = w[i * 32];
#pragma unroll
          for (int n = 0; n < NB; n++) acc[n] += sh[n][i] * wv;
        }
#pragma unroll
        for (int n = 0; n < NB; n++) sT[(n << 10) + pos] = acc[n];
      }
      __syncthreads();
      // edge pass over this quarter (sequential aq reads)
      const float* aqk = aq + (size_t)kc * nE * 32;
      int n = 0;
      for (int idx = cbase + sub; idx < cend; idx += 8) {
        while (idx >= s_rp[n + 1]) n++;
        const float4* a4 = (const float4*)(aqk + (size_t)idx * 32);
        const float* Tn = sT + (n << 10) + o;
        float s = 0.f;
#pragma unroll
        for (int kq = 0; kq < 8; kq++) {
          float4 av = a4[kq];
          s += av.x * Tn[(kq * 4 + 0) << 5];
          s += av.y * Tn[(kq * 4 + 1) << 5];
          s += av.z * Tn[(kq * 4 + 2) << 5];
          s += av.w * Tn[(kq * 4 + 3) << 5];
        }
        smsg[(idx - cbase) * 32 + o] += s;
      }
    }
    __syncthreads();  // msg complete
    // flush: one atomic per (edge, o)
    for (int idx = cbase + sub; idx < cend; idx += 8) {
      atomicAdd(&agg[(size_t)dstp[idx] * 32 + o], smsg[(idx - cbase) * 32 + o]);
    }
    __syncthreads();  // flush done before next chunk reuses smsg
  }
}

// ---------------- fused agg-read + GRU: block = 8 nodes x 32 o -------------
__global__ __launch_bounds__(256) void k_agru(
    const float* __restrict__ agg, const float* __restrict__ cbias,
    const float* __restrict__ wih, const float* __restrict__ whh,
    const float* __restrict__ bih, const float* __restrict__ bhh,
    float* __restrict__ hseq, int nV) {
  __shared__ float swT[2][32 * 97];  // transposed, stride-97 pad
  __shared__ float sb[2][96], scb[32];
  __shared__ float sx[8][32], shd[8][32];
  int t = threadIdx.x;
  int v0 = blockIdx.x * 8;
  for (int idx = t; idx < 3072; idx += 256) {
    int row = idx >> 5, i = idx & 31;
    swT[0][i * 97 + row] = wih[idx];
    swT[1][i * 97 + row] = whh[idx];
  }
  if (t < 96) { sb[0][t] = bih[t]; sb[1][t] = bhh[t]; }
  if (t < 32) scb[t] = cbias[t];
  {
    int n = t >> 5, v = v0 + n, j = t & 31;
    shd[n][j] = (v < nV) ? hseq[(size_t)v * 32 + j] : 0.f;
    sx[n][j] = (v < nV) ? fmaxf(agg[(size_t)v * 32 + j] + cbias[j], 0.f) : 0.f;
  }
  __syncthreads();
  int n = t >> 5, o = t & 31;
  int v = v0 + n;
  if (v >= nV) return;
  float gir = sb[0][o], giz = sb[0][32 + o], gin = sb[0][64 + o];
  float ghr = sb[1][o], ghz = sb[1][32 + o], ghn = sb[1][64 + o];
#pragma unroll
  for (int i = 0; i < 32; i++) {
    float xi = sx[n][i], hi = shd[n][i];
    gir += xi * swT[0][i * 97 + o];
    giz += xi * swT[0][i * 97 + 32 + o];
    gin += xi * swT[0][i * 97 + 64 + o];
    ghr += hi * swT[1][i * 97 + o];
    ghz += hi * swT[1][i * 97 + 32 + o];
    ghn += hi * swT[1][i * 97 + 64 + o];
  }
  float r = 1.f / (1.f + __expf(-(gir + ghr)));
  float z = 1.f / (1.f + __expf(-(giz + ghz)));
  float ng = tanhf(gin + r * ghn);
  hseq[(size_t)v * 32 + o] = (1.f - z) * ng + z * shd[n][o];
}

// ---------------- decoder: out = relu(h@dw1+db1)@dw2+db2  (V x 64) ---------
__global__ __launch_bounds__(256) void k_dec(
    const float* __restrict__ hseq, const float* __restrict__ w1,
    const float* __restrict__ b1, const float* __restrict__ w2,
    const float* __restrict__ b2, float* __restrict__ out, int nV) {
  __shared__ float sw1[1024], sb1[32], sw2[2048], sb2[64];
  __shared__ float sx[4][32], st1[4][32];
  int t = threadIdx.x;
  int v0 = blockIdx.x * 4;
  for (int i = t; i < 1024; i += 256) sw1[i] = w1[i];
  for (int i = t; i < 2048; i += 256) sw2[i] = w2[i];
  if (t < 32) sb1[t] = b1[t];
  if (t < 64) sb2[t] = b2[t];
  if (t < 128) {
    int g = v0 * 32 + t;
    sx[t >> 5][t & 31] = (g < nV * 32) ? hseq[g] : 0.f;
  }
  __syncthreads();
  if (t < 128) {
    int n = t >> 5, j = t & 31;
    float s = sb1[j];
#pragma unroll
    for (int i = 0; i < 32; i++) s += sx[n][i] * sw1[i * 32 + j];
    st1[n][j] = fmaxf(s, 0.f);
  }
  __syncthreads();
  int n = t >> 6, j = t & 63;
  float s = sb2[j];
#pragma unroll
  for (int i = 0; i < 32; i++) s += st1[n][i] * sw2[i * 64 + j];
  if (v0 + n < nV) out[(size_t)(v0 + n) * 64 + j] = s;
}

extern "C" void kernel_launch(void* const* d_in, const int* in_sizes, int n_in,
                              void* d_out, int out_size, void* d_ws, size_t ws_size,
                              hipStream_t stream) {
  const float* node_feats = (const float*)d_in[0];
  const float* edge_feats = (const float*)d_in[1];
  const int* src = (const int*)d_in[2];
  const int* dst = (const int*)d_in[3];
  const float* proj_w1 = (const float*)d_in[4];
  const float* proj_b1 = (const float*)d_in[5];
  const float* proj_w2 = (const float*)d_in[6];
  const float* proj_b2 = (const float*)d_in[7];
  const float* e_w1 = (const float*)d_in[8];
  const float* e_b1 = (const float*)d_in[9];
  const float* e_w2 = (const float*)d_in[10];
  const float* e_b2 = (const float*)d_in[11];
  const float* conv_bias = (const float*)d_in[12];
  const float* gru_wih = (const float*)d_in[13];
  const float* gru_whh = (const float*)d_in[14];
  const float* gru_bih = (const float*)d_in[15];
  const float* gru_bhh = (const float*)d_in[16];
  const float* dec_w1 = (const float*)d_in[17];
  const float* dec_b1 = (const float*)d_in[18];
  const float* dec_w2 = (const float*)d_in[19];
  const float* dec_b2 = (const float*)d_in[20];
  float* out = (float*)d_out;

  const int nV = in_sizes[0] / 32;
  const int nE = in_sizes[2];

  // workspace carve-up (~110 MB; known-safe)
  char* base = (char*)d_ws;
  size_t off = 0;
  auto carve = [&](size_t bytes) {
    void* r = base + off;
    off = (off + bytes + 255) & ~(size_t)255;
    return r;
  };
  float* aq = (float*)carve((size_t)4 * nE * 32 * 4);  // [kc][idx][o32]
  float* hseq = (float*)carve((size_t)nV * 32 * 4);
  float* agg = (float*)carve((size_t)nV * 32 * 4);
  int* countsS = (int*)carve((size_t)nV * 4);
  int* rpS = (int*)carve((size_t)(nV + 1) * 4);
  int* curS = (int*)carve((size_t)nV * 4);
  int* permS = (int*)carve((size_t)nE * 4);
  int* dstp = (int*)carve((size_t)nE * 4);
  (void)ws_size;

  const int TB = 256;
  int gE = (nE + TB - 1) / TB;
  int g8 = (nV + 7) / 8;
  int g4 = (nV + 3) / 4;
  int gStep = (nV + NB - 1) / NB;

  // setup
  k_proj<<<g8, TB, 0, stream>>>(node_feats, proj_w1, proj_b1, proj_w2, proj_b2, hseq, nV);
  hipMemsetAsync(countsS, 0, (size_t)nV * 4, stream);
  k_count<<<gE, TB, 0, stream>>>(src, countsS, nE);
  k_scan<<<1, 1024, 0, stream>>>(countsS, rpS, nV);
  k_copy<<<(nV + TB - 1) / TB, TB, 0, stream>>>(rpS, curS, nV);
  k_scatter<<<gE, TB, 0, stream>>>(src, dst, curS, permS, dstp, nE);
  k_edgeha<<<(nE + 1) / 2, TB, 0, stream>>>(edge_feats, e_w1, e_b1, permS, aq, nE);

  // 6 message-passing steps
  for (int step = 0; step < 6; step++) {
    hipMemsetAsync(agg, 0, (size_t)nV * 32 * 4, stream);
    k_step<<<gStep, TB, 0, stream>>>(hseq, e_w2, e_b2, aq, rpS, dstp, agg, nV, nE);
    k_agru<<<g8, TB, 0, stream>>>(agg, conv_bias, gru_wih, gru_whh,
                                  gru_bih, gru_bhh, hseq, nV);
  }

  // decoder
  k_dec<<<g4, TB, 0, stream>>>(hseq, dec_w1, dec_b1, dec_w2, dec_b2, out, nV);
}

// Round 8
// 1381.718 us; speedup vs baseline: 1.5352x; 1.0585x over previous
//
#include <hip/hip_runtime.h>
#include <hip/hip_bf16.h>

// MPNN GNN: V=12500 (feat 32), E=200000 (feat 16), H=32, 6 steps.
// msg[e,o] = sum_k a[e,k]*T[src[e],k,o] + Tb[src[e],o],  a loop-invariant.
// R7 analysis: k_step = VALU-FMA ~125us (T 63 + edge 62) || LDS-pipe ~121us
// (12.8M ds_read_b32). R8: cut LDS via 8-edge "octs" with uniform src:
//  - CSR padded to multiples of 8 per node (rp8, dstp=-1 sentinels, a=0)
//  - a transposed to aq_t[k][idx] -> oct a-values contiguous -> LDS-staged,
//    read as uniform-address b128 broadcasts
//  - per (oct,kl): 1 b32 T-read (2-way bcast, bank=o) + 2 bcast b128 + 8 FMA
//  - smsg LDS accumulate, single atomic per real (e,o) at flush

#define NB 4     // src nodes per k_step block
#define CAP 128  // edge chunk (multiple of 8)
#define SA_W 136 // sA row stride (floats)

// ---------------- node projection: h = relu(nf@w1+b1)@w2+b2 ----------------
__global__ __launch_bounds__(256) void k_proj(
    const float* __restrict__ nf, const float* __restrict__ w1,
    const float* __restrict__ b1, const float* __restrict__ w2,
    const float* __restrict__ b2, float* __restrict__ hseq, int nV) {
  __shared__ float sw1[1024], sw2[1024], sb1[32], sb2[32];
  __shared__ float sx[8][32], st1[8][32];
  int t = threadIdx.x;
  int v0 = blockIdx.x * 8;
  for (int i = t; i < 1024; i += 256) { sw1[i] = w1[i]; sw2[i] = w2[i]; }
  if (t < 32) { sb1[t] = b1[t]; sb2[t] = b2[t]; }
  {
    int g = v0 * 32 + t;
    sx[t >> 5][t & 31] = (g < nV * 32) ? nf[g] : 0.f;
  }
  __syncthreads();
  int n = t >> 5, j = t & 31;
  float s = sb1[j];
#pragma unroll
  for (int i = 0; i < 32; i++) s += sx[n][i] * sw1[i * 32 + j];
  st1[n][j] = fmaxf(s, 0.f);
  __syncthreads();
  float h = sb2[j];
#pragma unroll
  for (int i = 0; i < 32; i++) h += st1[n][i] * sw2[i * 32 + j];
  if (v0 + n < nV) hseq[(size_t)(v0 + n) * 32 + j] = h;
}

// ---------------- CSR by src, padded to multiples of 8 ---------------------
__global__ __launch_bounds__(256) void k_count(const int* __restrict__ key,
                                               int* __restrict__ counts, int nE) {
  int e = blockIdx.x * 256 + threadIdx.x;
  if (e < nE) atomicAdd(&counts[key[e]], 1);
}

__global__ __launch_bounds__(1024) void k_scan(const int* __restrict__ counts,
                                               int* __restrict__ row_ptr, int nV) {
  __shared__ int buf[1024];
  __shared__ int s_off;
  int t = threadIdx.x;
  if (t == 0) s_off = 0;
  __syncthreads();
  for (int base = 0; base < nV; base += 1024) {
    int x = (base + t < nV) ? ((counts[base + t] + 7) & ~7) : 0;  // pad to 8
    buf[t] = x;
    __syncthreads();
    for (int d = 1; d < 1024; d <<= 1) {
      int v2 = (t >= d) ? buf[t - d] : 0;
      __syncthreads();
      buf[t] += v2;
      __syncthreads();
    }
    int incl = buf[t];
    int off = s_off;
    __syncthreads();
    if (base + t < nV) row_ptr[base + t] = off + incl - x;  // exclusive
    if (t == 1023) s_off = off + incl;
    __syncthreads();
  }
  if (t == 0) row_ptr[nV] = s_off;
}

__global__ __launch_bounds__(256) void k_copy(const int* __restrict__ row_ptr,
                                              int* __restrict__ cursor, int nV) {
  int v = blockIdx.x * 256 + threadIdx.x;
  if (v < nV) cursor[v] = row_ptr[v];
}

// scatter: perm[p]=edge id, dstp[p]=dst (dstp pre-memset to -1 for pads)
__global__ __launch_bounds__(256) void k_scatter(const int* __restrict__ key,
                                                 const int* __restrict__ dst,
                                                 int* __restrict__ cursor,
                                                 int* __restrict__ perm,
                                                 int* __restrict__ dstp, int nE) {
  int e = blockIdx.x * 256 + threadIdx.x;
  if (e < nE) {
    int p = atomicAdd(&cursor[key[e]], 1);
    perm[p] = e;
    dstp[p] = dst[e];
  }
}

// ---------------- edge MLP -> transposed aq_t[k][idx], pads = 0 ------------
// Block = 128 padded-idx tile. LDS transpose for coalesced row writes.
__global__ __launch_bounds__(256) void k_edgebuild(
    const float* __restrict__ ef, const float* __restrict__ w1,
    const float* __restrict__ b1, const int* __restrict__ perm,
    const int* __restrict__ dstp, const int* __restrict__ rp8,
    float* __restrict__ aq_t, int nV, int S) {
  __shared__ float sw1[16 * 128], sb1[128];
  __shared__ float sef[128][17];
  __shared__ float sa[128][128];
  __shared__ int spad[128];
  int t = threadIdx.x;
  for (int i = t; i < 2048; i += 256) sw1[i] = w1[i];
  if (t < 128) sb1[t] = b1[t];
  int total = rp8[nV];
  int i0 = blockIdx.x * 128;
  if (i0 >= total) return;
  {
    int r = t >> 1, half = t & 1;
    int idx = i0 + r;
    bool pad = (idx >= total) || (dstp[idx] < 0);
    if (half == 0) spad[r] = pad ? 1 : 0;
    const float* src = pad ? ef : ef + (size_t)perm[idx] * 16;
#pragma unroll
    for (int j = 0; j < 8; j++) sef[r][half * 8 + j] = pad ? 0.f : src[half * 8 + j];
  }
  __syncthreads();
#pragma unroll 4
  for (int i = 0; i < 64; i++) {
    int cell = i * 256 + t;
    int c = cell >> 7, le = cell & 127;
    float s = sb1[c];
#pragma unroll
    for (int j = 0; j < 16; j++) s += sef[le][j] * sw1[j * 128 + c];
    sa[c][le] = spad[le] ? 0.f : fmaxf(s, 0.f);
  }
  __syncthreads();
#pragma unroll 4
  for (int i = 0; i < 64; i++) {
    int cell = i * 256 + t;
    int r = cell >> 7, le = cell & 127;
    aq_t[(size_t)r * S + i0 + le] = sa[r][le];
  }
}

// ---------------- per-step: T-in-LDS + oct edge loop + smsg + atomics ------
__global__ __launch_bounds__(256) void k_step(
    const float* __restrict__ hseq, const float* __restrict__ w2,
    const float* __restrict__ b2, const float* __restrict__ aq_t,
    const int* __restrict__ rp8, const int* __restrict__ dstp,
    float* __restrict__ agg, int nV, int S) {
  __shared__ float sT[NB * 1024];   // [n][kl][o] quarter, bank = o
  __shared__ float sA[32 * SA_W];   // [kl][le]
  __shared__ float smsg[CAP * 32];  // [le][o]
  __shared__ float sh[NB][32];
  __shared__ float sTb[NB][32];
  __shared__ int s_rp[NB + 1];
  int t = threadIdx.x;
  int v0 = blockIdx.x * NB;
  if (t <= NB) {
    int v = v0 + t;
    if (v > nV) v = nV;
    s_rp[t] = rp8[v];
  }
  if (t < NB * 32) {
    int n = t >> 5, v = v0 + n;
    sh[n][t & 31] = (v < nV) ? hseq[(size_t)v * 32 + (t & 31)] : 0.f;
  }
  __syncthreads();
  int beg = s_rp[0], end = s_rp[NB];
  if (beg == end) return;  // block-uniform

  if (t < NB * 32) {  // Tb
    int n = t >> 5, o = t & 31;
    float s = 0.f;
#pragma unroll
    for (int i = 0; i < 32; i++) s += sh[n][i] * b2[i * 32 + o];
    sTb[n][o] = s;
  }

  int o = t & 31, sub = t >> 5;

  for (int cbase = beg; cbase < end; cbase += CAP) {
    int cend = cbase + CAP < end ? cbase + CAP : end;
    __syncthreads();  // prev flush done (and sTb ready on first pass)
    for (int i = t; i < CAP * 32; i += 256) smsg[i] = 0.f;

    for (int kc = 0; kc < 4; kc++) {
      __syncthreads();  // smsg zero / prev edge pass done before overwrite
      // T-quarter [n][kl][o]
      for (int pos = t; pos < 1024; pos += 256) {
        int kl = pos >> 5, oo = pos & 31;
        const float* w = w2 + (size_t)(kc * 32 + kl) * 1024 + oo;  // + i*32
        float acc[NB];
#pragma unroll
        for (int n = 0; n < NB; n++) acc[n] = 0.f;
#pragma unroll 8
        for (int i = 0; i < 32; i++) {
          float wv = w[i * 32];
#pragma unroll
          for (int n = 0; n < NB; n++) acc[n] += sh[n][i] * wv;
        }
#pragma unroll
        for (int n = 0; n < NB; n++) sT[(n << 10) + pos] = acc[n];
      }
      // stage sA: 32 rows x CAP floats (coalesced; pads already 0 in aq_t)
      {
        int kl = t >> 3, c0 = (t & 7) * 16;
        const float4* s4 = (const float4*)(aq_t + (size_t)(kc * 32 + kl) * S + cbase + c0);
        float4* d4 = (float4*)(sA + kl * SA_W + c0);
        d4[0] = s4[0]; d4[1] = s4[1]; d4[2] = s4[2]; d4[3] = s4[3];
      }
      __syncthreads();
      // oct edge pass: sub s owns octs j0 = cbase + s*8 + 64m
      int n = 0;
      for (int j0 = cbase + sub * 8; j0 < cend; j0 += 64) {
        while (j0 >= s_rp[n + 1]) n++;
        int le0 = j0 - cbase;
        float acc0 = 0.f, acc1 = 0.f, acc2 = 0.f, acc3 = 0.f;
        float acc4 = 0.f, acc5 = 0.f, acc6 = 0.f, acc7 = 0.f;
        const float* Tn = sT + (n << 10) + o;
        const float4* aBase = (const float4*)(sA + le0);
#pragma unroll 8
        for (int kl = 0; kl < 32; kl++) {
          float tv = Tn[kl << 5];
          float4 x = aBase[kl * (SA_W / 4)];
          float4 y = aBase[kl * (SA_W / 4) + 1];
          acc0 += x.x * tv; acc1 += x.y * tv; acc2 += x.z * tv; acc3 += x.w * tv;
          acc4 += y.x * tv; acc5 += y.y * tv; acc6 += y.z * tv; acc7 += y.w * tv;
        }
        float* m = smsg + le0 * 32 + o;
        m[0 * 32] += acc0; m[1 * 32] += acc1; m[2 * 32] += acc2; m[3 * 32] += acc3;
        m[4 * 32] += acc4; m[5 * 32] += acc5; m[6 * 32] += acc6; m[7 * 32] += acc7;
      }
    }
    __syncthreads();  // msg complete
    // flush: one atomic per real (edge, o), + Tb
    {
      int n = 0;
      for (int idx = cbase + sub; idx < cend; idx += 8) {
        while (idx >= s_rp[n + 1]) n++;
        int d = dstp[idx];
        if (d >= 0)
          atomicAdd(&agg[(size_t)d * 32 + o], smsg[(idx - cbase) * 32 + o] + sTb[n][o]);
      }
    }
  }
}

// ---------------- fused agg-read + GRU: block = 8 nodes x 32 o -------------
__global__ __launch_bounds__(256) void k_agru(
    const float* __restrict__ agg, const float* __restrict__ cbias,
    const float* __restrict__ wih, const float* __restrict__ whh,
    const float* __restrict__ bih, const float* __restrict__ bhh,
    float* __restrict__ hseq, int nV) {
  __shared__ float swT[2][32 * 97];
  __shared__ float sb[2][96], scb[32];
  __shared__ float sx[8][32], shd[8][32];
  int t = threadIdx.x;
  int v0 = blockIdx.x * 8;
  for (int idx = t; idx < 3072; idx += 256) {
    int row = idx >> 5, i = idx & 31;
    swT[0][i * 97 + row] = wih[idx];
    swT[1][i * 97 + row] = whh[idx];
  }
  if (t < 96) { sb[0][t] = bih[t]; sb[1][t] = bhh[t]; }
  if (t < 32) scb[t] = cbias[t];
  {
    int n = t >> 5, v = v0 + n, j = t & 31;
    shd[n][j] = (v < nV) ? hseq[(size_t)v * 32 + j] : 0.f;
    sx[n][j] = (v < nV) ? fmaxf(agg[(size_t)v * 32 + j] + cbias[j], 0.f) : 0.f;
  }
  __syncthreads();
  int n = t >> 5, o = t & 31;
  int v = v0 + n;
  if (v >= nV) return;
  float gir = sb[0][o], giz = sb[0][32 + o], gin = sb[0][64 + o];
  float ghr = sb[1][o], ghz = sb[1][32 + o], ghn = sb[1][64 + o];
#pragma unroll
  for (int i = 0; i < 32; i++) {
    float xi = sx[n][i], hi = shd[n][i];
    gir += xi * swT[0][i * 97 + o];
    giz += xi * swT[0][i * 97 + 32 + o];
    gin += xi * swT[0][i * 97 + 64 + o];
    ghr += hi * swT[1][i * 97 + o];
    ghz += hi * swT[1][i * 97 + 32 + o];
    ghn += hi * swT[1][i * 97 + 64 + o];
  }
  float r = 1.f / (1.f + __expf(-(gir + ghr)));
  float z = 1.f / (1.f + __expf(-(giz + ghz)));
  float ng = tanhf(gin + r * ghn);
  hseq[(size_t)v * 32 + o] = (1.f - z) * ng + z * shd[n][o];
}

// ---------------- decoder: out = relu(h@dw1+db1)@dw2+db2  (V x 64) ---------
__global__ __launch_bounds__(256) void k_dec(
    const float* __restrict__ hseq, const float* __restrict__ w1,
    const float* __restrict__ b1, const float* __restrict__ w2,
    const float* __restrict__ b2, float* __restrict__ out, int nV) {
  __shared__ float sw1[1024], sb1[32], sw2[2048], sb2[64];
  __shared__ float sx[4][32], st1[4][32];
  int t = threadIdx.x;
  int v0 = blockIdx.x * 4;
  for (int i = t; i < 1024; i += 256) sw1[i] = w1[i];
  for (int i = t; i < 2048; i += 256) sw2[i] = w2[i];
  if (t < 32) sb1[t] = b1[t];
  if (t < 64) sb2[t] = b2[t];
  if (t < 128) {
    int g = v0 * 32 + t;
    sx[t >> 5][t & 31] = (g < nV * 32) ? hseq[g] : 0.f;
  }
  __syncthreads();
  if (t < 128) {
    int n = t >> 5, j = t & 31;
    float s = sb1[j];
#pragma unroll
    for (int i = 0; i < 32; i++) s += sx[n][i] * sw1[i * 32 + j];
    st1[n][j] = fmaxf(s, 0.f);
  }
  __syncthreads();
  int n = t >> 6, j = t & 63;
  float s = sb2[j];
#pragma unroll
  for (int i = 0; i < 32; i++) s += st1[n][i] * sw2[i * 64 + j];
  if (v0 + n < nV) out[(size_t)(v0 + n) * 64 + j] = s;
}

extern "C" void kernel_launch(void* const* d_in, const int* in_sizes, int n_in,
                              void* d_out, int out_size, void* d_ws, size_t ws_size,
                              hipStream_t stream) {
  const float* node_feats = (const float*)d_in[0];
  const float* edge_feats = (const float*)d_in[1];
  const int* src = (const int*)d_in[2];
  const int* dst = (const int*)d_in[3];
  const float* proj_w1 = (const float*)d_in[4];
  const float* proj_b1 = (const float*)d_in[5];
  const float* proj_w2 = (const float*)d_in[6];
  const float* proj_b2 = (const float*)d_in[7];
  const float* e_w1 = (const float*)d_in[8];
  const float* e_b1 = (const float*)d_in[9];
  const float* e_w2 = (const float*)d_in[10];
  const float* e_b2 = (const float*)d_in[11];
  const float* conv_bias = (const float*)d_in[12];
  const float* gru_wih = (const float*)d_in[13];
  const float* gru_whh = (const float*)d_in[14];
  const float* gru_bih = (const float*)d_in[15];
  const float* gru_bhh = (const float*)d_in[16];
  const float* dec_w1 = (const float*)d_in[17];
  const float* dec_b1 = (const float*)d_in[18];
  const float* dec_w2 = (const float*)d_in[19];
  const float* dec_b2 = (const float*)d_in[20];
  float* out = (float*)d_out;

  const int nV = in_sizes[0] / 32;
  const int nE = in_sizes[2];
  // padded idx space upper bound (host-known, multiple of 32)
  const int S = (nE + 8 * nV + 159) & ~31;

  // workspace carve-up (~161 MB; known-safe budget ~211)
  char* base = (char*)d_ws;
  size_t off = 0;
  auto carve = [&](size_t bytes) {
    void* r = base + off;
    off = (off + bytes + 255) & ~(size_t)255;
    return r;
  };
  float* aq_t = (float*)carve((size_t)S * 128 * 4);  // [k][idx]
  float* hseq = (float*)carve((size_t)nV * 32 * 4);
  float* agg = (float*)carve((size_t)nV * 32 * 4);
  int* countsS = (int*)carve((size_t)nV * 4);
  int* rp8 = (int*)carve((size_t)(nV + 1) * 4);
  int* curS = (int*)carve((size_t)nV * 4);
  int* permS = (int*)carve((size_t)S * 4);
  int* dstp = (int*)carve((size_t)S * 4);
  (void)ws_size;

  const int TB = 256;
  int gE = (nE + TB - 1) / TB;
  int g8 = (nV + 7) / 8;
  int g4 = (nV + 3) / 4;
  int gStep = (nV + NB - 1) / NB;
  int gBuild = (S + 127) / 128;

  // setup
  k_proj<<<g8, TB, 0, stream>>>(node_feats, proj_w1, proj_b1, proj_w2, proj_b2, hseq, nV);
  hipMemsetAsync(countsS, 0, (size_t)nV * 4, stream);
  hipMemsetAsync(dstp, 0xFF, (size_t)S * 4, stream);  // -1 sentinels
  k_count<<<gE, TB, 0, stream>>>(src, countsS, nE);
  k_scan<<<1, 1024, 0, stream>>>(countsS, rp8, nV);
  k_copy<<<(nV + TB - 1) / TB, TB, 0, stream>>>(rp8, curS, nV);
  k_scatter<<<gE, TB, 0, stream>>>(src, dst, curS, permS, dstp, nE);
  k_edgebuild<<<gBuild, TB, 0, stream>>>(edge_feats, e_w1, e_b1, permS, dstp, rp8,
                                         aq_t, nV, S);

  // 6 message-passing steps
  for (int step = 0; step < 6; step++) {
    hipMemsetAsync(agg, 0, (size_t)nV * 32 * 4, stream);
    k_step<<<gStep, TB, 0, stream>>>(hseq, e_w2, e_b2, aq_t, rp8, dstp, agg, nV, S);
    k_agru<<<g8, TB, 0, stream>>>(agg, conv_bias, gru_wih, gru_whh,
                                  gru_bih, gru_bhh, hseq, nV);
  }

  // decoder
  k_dec<<<g4, TB, 0, stream>>>(hseq, dec_w1, dec_b1, dec_w2, dec_b2, out, nV);
}